// Round 1
// baseline (674.412 us; speedup 1.0000x reference)
//
#include <hip/hip_runtime.h>

#define NSUB 4096
#define DIM 64
#define NROW 8192
#define KTOP 20

typedef unsigned long long u64;

// -------------------------------------------------------------------------
// K1: V[k] = emb[k] @ w[k] + b[k], computed in f64 from f32 inputs.
//   which==0 -> V1 row-major  [4][4096][64]
//   which==1 -> V2T transposed [4][64][4096]  (for coalesced column streaming)
// grid 512 (= 2 which * 4 k * 64 tiles), block 256, dynamic LDS 66560 B.
// -------------------------------------------------------------------------
__global__ void k_compute_v(const float* __restrict__ emb1, const float* __restrict__ w1,
                            const float* __restrict__ b1,
                            const float* __restrict__ emb2, const float* __restrict__ w2,
                            const float* __restrict__ b2,
                            double* __restrict__ V1, double* __restrict__ V2T) {
    extern __shared__ char smem[];
    float* embS = (float*)smem;           // 64*64 f32 = 16384 B
    float* wS   = embS + 64 * 64;         // 16384 B
    float* bS   = wS + 64 * 64;           // 256 B
    double* CS  = (double*)(smem + 33280); // 64*65 f64 = 33280 B (padded stride 65)

    int bx    = blockIdx.x;
    int which = bx >> 8;        // 0: V1, 1: V2T
    int rem   = bx & 255;
    int k     = rem >> 6;       // block 0..3
    int tile  = rem & 63;       // 64-row tile
    int n0    = tile * 64;

    const float* emb = which ? emb2 : emb1;
    const float* w   = which ? w2 : w1;
    const float* b   = which ? b2 : b1;

    int tid = threadIdx.x;
    const float* esrc = emb + ((size_t)k * NSUB + n0) * DIM;
    const float* wsrc = w + (size_t)k * DIM * DIM;
    for (int t = tid; t < 64 * 64; t += 256) { embS[t] = esrc[t]; wS[t] = wsrc[t]; }
    if (tid < 64) bS[tid] = b[k * 64 + tid];
    __syncthreads();

    int e    = tid & 63;
    int mrow = tid >> 6;

    double accs[16];
#pragma unroll
    for (int it = 0; it < 16; ++it) {
        int m = mrow * 16 + it;
        double acc = (double)bS[e];
        for (int d = 0; d < 64; ++d)
            acc += (double)embS[m * 64 + d] * (double)wS[d * 64 + e];
        accs[it] = acc;
    }

    if (which == 0) {
#pragma unroll
        for (int it = 0; it < 16; ++it) {
            int m = mrow * 16 + it;
            V1[((size_t)k * NSUB + n0 + m) * DIM + e] = accs[it];
        }
    } else {
#pragma unroll
        for (int it = 0; it < 16; ++it) {
            int m = mrow * 16 + it;
            CS[m * 65 + e] = accs[it];
        }
        __syncthreads();
        int m2 = tid & 63;
        int eg = tid >> 6;
#pragma unroll
        for (int it = 0; it < 16; ++it) {
            int e2 = eg * 16 + it;
            V2T[((size_t)k * DIM + e2) * NSUB + n0 + m2] = CS[m2 * 65 + e2];
        }
    }
}

// -------------------------------------------------------------------------
// K2: streaming per-row top-20. grid 512 (16 rows each), block 256 (4 waves).
// Each wave owns 4 rows; the sorted top-20 list per row lives across lanes
// 0..19 in registers as packed keys: (f64 bits of max(a,0) & ~0x1FFF) |
// (8191 - col). Larger value wins; tie -> lower col (== lax.top_k).
// Selection on raw `a` (tanh monotone); tanh applied only to survivors.
// -------------------------------------------------------------------------
__global__ __launch_bounds__(256) void k_topk(const double* __restrict__ V1,
                                              const double* __restrict__ V2T,
                                              int* __restrict__ outIdx,
                                              float* __restrict__ outVal) {
    __shared__ double v1s[16 * 2 * 64];   // 16 KB: [row-in-wg][j][d]

    int tid = threadIdx.x;
    int r0  = blockIdx.x * 16;
    int i   = r0 >> 12;
    int n0  = r0 & (NSUB - 1);

    for (int t = tid; t < 2048; t += 256) {
        int rr = t >> 7, j = (t >> 6) & 1, d = t & 63;
        v1s[t] = V1[((size_t)(2 * i + j) * NSUB + n0 + rr) * DIM + d];
    }
    __syncthreads();

    int l = tid & 63;
    int w = tid >> 6;
    int rbase = 4 * w;                    // this wave's rows (in-wg): rbase..rbase+3

    u64 lst[4] = {0, 0, 0, 0};            // lane<20: rank-l entry of each row's list
    u64 th[4]  = {0, 0, 0, 0};            // current 20th key per row

    for (int ch = 0; ch < 32; ++ch) {
        int cb = ch * 256;
        int j  = cb >> 12;
        int mh = (cb & (NSUB - 1)) + l * 4;
        const double* p   = V2T + ((size_t)(2 * i + j) * DIM) * NSUB + mh;
        const double* v1p = &v1s[(rbase * 2 + j) * 64];

        double acc[4][4];
#pragma unroll
        for (int a = 0; a < 4; ++a)
#pragma unroll
            for (int c = 0; c < 4; ++c) acc[a][c] = 0.0;

        for (int d = 0; d < 64; ++d) {
            double b0 = p[0], b1v = p[1], b2v = p[2], b3v = p[3];
#pragma unroll
            for (int rr = 0; rr < 4; ++rr) {
                double a1 = v1p[rr * 128 + d];
                acc[rr][0] += a1 * b0;
                acc[rr][1] += a1 * b1v;
                acc[rr][2] += a1 * b2v;
                acc[rr][3] += a1 * b3v;
            }
            p += NSUB;
        }

#pragma unroll
        for (int rr = 0; rr < 4; ++rr) {
#pragma unroll
            for (int cc = 0; cc < 4; ++cc) {
                int c = cb + l * 4 + cc;
                double a = acc[rr][cc] > 0.0 ? acc[rr][cc] : 0.0;
                u64 bits = (u64)__double_as_longlong(a);
                u64 cand = (bits & ~0x1FFFull) | (u64)(8191 - c);
                // serialized wave-cooperative insertion (rare after warm-up)
                while (true) {
                    u64 m = __ballot(cand > th[rr]);
                    if (m == 0) break;
                    int src = __ffsll(m) - 1;
                    u64 kk = (u64)__shfl((long long)cand, src);
                    u64 e  = lst[rr];
                    u64 up = (u64)__shfl_up((long long)e, 1);
                    int pos = __popcll(__ballot(e > kk)); // lanes>=20 hold 0 < kk
                    u64 ne = (l < pos) ? e : ((l == pos) ? kk : up);
                    if (l < 20) lst[rr] = ne;
                    th[rr] = (u64)__shfl((long long)lst[rr], 19);
                    if (l == src) cand = 0;
                }
            }
        }
    }

    if (l < 20) {
#pragma unroll
        for (int rr = 0; rr < 4; ++rr) {
            u64 key = lst[rr];
            int c = 8191 - (int)(key & 0x1FFFull);
            double a = __longlong_as_double((long long)(key & ~0x1FFFull));
            float val = (a > 0.0) ? (float)tanh(3.0 * a) : 0.0f;
            size_t g = ((size_t)(r0 + rbase + rr)) * KTOP + l;
            outIdx[g] = c;
            outVal[g] = val;
        }
    }
}

// -------------------------------------------------------------------------
// K3: scatter 8192*20 survivors into the zeroed output.
// -------------------------------------------------------------------------
__global__ void k_scatter(const int* __restrict__ outIdx, const float* __restrict__ outVal,
                          float* __restrict__ out) {
    int t = blockIdx.x * 256 + threadIdx.x;
    if (t >= NROW * KTOP) return;
    int row = t / KTOP;
    int c = outIdx[t];
    out[(size_t)row * NROW + c] = outVal[t];
}

extern "C" void kernel_launch(void* const* d_in, const int* in_sizes, int n_in,
                              void* d_out, int out_size, void* d_ws, size_t ws_size,
                              hipStream_t stream) {
    // setup_inputs order: idx, emb1, emb2, w1, w2, b1, b2 (all f32 except idx)
    const float* emb1 = (const float*)d_in[1];
    const float* emb2 = (const float*)d_in[2];
    const float* w1   = (const float*)d_in[3];
    const float* w2   = (const float*)d_in[4];
    const float* b1   = (const float*)d_in[5];
    const float* b2   = (const float*)d_in[6];
    float* out = (float*)d_out;

    // f64 V staging lives in the head of d_out (16 MB of 256 MB); it is
    // consumed by k_topk, then the full output is zeroed and scattered.
    double* V1  = (double*)d_out;
    double* V2T = V1 + (size_t)4 * NSUB * DIM;    // +8 MB

    int*   outIdx = (int*)d_ws;                               // 640 KB
    float* outVal = (float*)((char*)d_ws + (size_t)NROW * KTOP * sizeof(int));

    hipLaunchKernelGGL(k_compute_v, dim3(512), dim3(256), 66560, stream,
                       emb1, w1, b1, emb2, w2, b2, V1, V2T);
    hipLaunchKernelGGL(k_topk, dim3(512), dim3(256), 0, stream, V1, V2T, outIdx, outVal);
    hipMemsetAsync(d_out, 0, (size_t)out_size * sizeof(float), stream);
    hipLaunchKernelGGL(k_scatter, dim3((NROW * KTOP + 255) / 256), dim3(256), 0, stream,
                       outIdx, outVal, out);
}